// Round 6
// baseline (421.370 us; speedup 1.0000x reference)
//
#include <hip/hip_runtime.h>
#include <hip/hip_bf16.h>
#include <cmath>

#define NB 16
#define NL 64
#define NP 512
#define NH 128
#define NG 10
#define ROWS (NB * NL * NP)          // 524288 rows

// output layout (flat float32, reference return order)
#define OFF_PI    ((size_t)0)
#define OFF_SIGMA ((size_t)5242880)
#define OFF_MU    ((size_t)10485760)
#define OFF_DIST  ((size_t)15728640)
#define OFF_MASK  ((size_t)16252928)

typedef __attribute__((ext_vector_type(8))) short short8;  // 8 bf16 = 4 VGPR
typedef __attribute__((ext_vector_type(4))) float f32x4;   // MFMA acc

// f32 -> bf16 (RNE) via compiler cast: emits v_cvt_pk_bf16_f32 pairs
__device__ __forceinline__ short bfc(float x) {
    return (short)__builtin_bit_cast(unsigned short, __float2bfloat16(x));
}

// ---------------------------------------------------------------------------
// Fused kernel: min-dist over 24 atoms + 3x GEMV [128 -> 30] + activations.
//
// R6 (on top of R5's MFMA structure):
//  - all 64 weight loads hoisted before the dist part (L2 latency hides
//    under dist's VALU work); B-fragments pre-packed once per thread
//  - 2-deep software pipeline over ks: X-loads for ks+1 are in flight
//    while ks's fragments convert + MFMA (R5's unroll-1 loop exposed
//    ~4x900cy of serial HBM latency per wave at ~3 waves/SIMD)
//  - bf16 conversion via __float2bfloat16 (v_cvt_pk) instead of 5-op
//    integer emulation (~450 VALU ops/thread removed)
// Outputs packed as 32 cols [pi(10)|sg(10)|mu(10)|pad(2)]; per wave
// 4 M-tiles x 2 N-tiles x 4 K-steps = 32 MFMAs. A/B packed with the same
// k-map so any HW k-permutation cancels (verified: R5 passed).
// C/D layout (m89/m91): col=lane&15, row=(lane>>4)*4+reg.
// ---------------------------------------------------------------------------
__global__ __launch_bounds__(256, 3) void k_fused(
    const float* __restrict__ pos_l,   // [B, NL, 3]
    const float* __restrict__ pos_p,   // [B, NP, 24, 3]
    const int*   __restrict__ mask,    // [B, NL, NP] (bool as int32)
    const float* __restrict__ X,       // [ROWS, 128]
    const float* __restrict__ Wpi, const float* __restrict__ bpi,
    const float* __restrict__ Wsg, const float* __restrict__ bsg,
    const float* __restrict__ Wmu, const float* __restrict__ bmu,
    float* __restrict__ out_pi,
    float* __restrict__ out_sg,
    float* __restrict__ out_mu,
    float* __restrict__ dist_out,
    float* __restrict__ mask_out)
{
    // per-wave C regions: [4 waves][64 rows][36 cols] f32 = 36864 B
    __shared__ __align__(16) float cs[4 * 64 * 36];

    const int tid  = threadIdx.x;
    const int wv   = tid >> 6;
    const int lane = tid & 63;
    const int lrow = lane & 15;              // A-row / C-col within tile
    const int lkg  = lane >> 4;              // k-group (8 k each)
    const int idx  = blockIdx.x * 256 + tid; // b*NL*NP + l*NP + p
    const size_t row0 = (size_t)blockIdx.x * 256;

    // ---------------- per-lane column mapping (packed cols) ----------------
    // col c: 0-9 pi | 10-19 sigma | 20-29 mu | 30,31 pad
    const int c0 = lrow;
    const int c1 = lrow + 16;
    const float* wb0; float bv0;
    if (c0 < 10) { wb0 = Wpi + c0;      bv0 = bpi[c0]; }
    else         { wb0 = Wsg + c0 - 10; bv0 = bsg[c0 - 10]; }
    const float* wb1; float bv1; bool pad1;
    if (c1 < 20)      { wb1 = Wsg + c1 - 10; bv1 = bsg[c1 - 10]; pad1 = false; }
    else if (c1 < 30) { wb1 = Wmu + c1 - 20; bv1 = bmu[c1 - 20]; pad1 = false; }
    else              { wb1 = Wpi;           bv1 = 0.0f;         pad1 = true; }

    // ---- issue ALL weight loads up front (latency hides under dist) ----
    float w0v[32], w1v[32];
    #pragma unroll
    for (int ks = 0; ks < 4; ++ks)
        #pragma unroll
        for (int j = 0; j < 8; ++j) {
            int k = ks * 32 + lkg * 8 + j;
            w0v[ks * 8 + j] = wb0[k * NG];
            w1v[ks * 8 + j] = wb1[k * NG];
        }

    // ---- issue ks=0 X loads (in flight across dist as well) ----
    const float* xbase = X + (row0 + wv * 64 + lrow) * NH + lkg * 8;
    float4 xc0[4], xc1[4];
    #pragma unroll
    for (int m = 0; m < 4; ++m) {
        const float* ap = xbase + (size_t)m * 16 * NH;
        xc0[m] = *(const float4*)ap;
        xc1[m] = *(const float4*)(ap + 4);
    }

    // ---------------- distance part ----------------
    {
        int p  = idx & (NP - 1);
        int bl = idx >> 9;                   // b*NL + l
        int b  = bl >> 6;

        const float* xl = pos_l + bl * 3;
        float x0 = xl[0], x1 = xl[1], x2 = xl[2];
        float qs = x0 * x0 + x1 * x1 + x2 * x2;

        const float4* yp = (const float4*)(pos_p + ((size_t)(b * NP + p)) * 72);

        // d2<0 -> NaN -> 10000 in the ref: clamp to 1e8 (=10000^2 exactly),
        // one sqrt of the min at the end.
        float m2 = 1e30f;
        #pragma unroll
        for (int q = 0; q < 6; ++q) {
            float4 v0 = yp[q * 3 + 0];
            float4 v1 = yp[q * 3 + 1];
            float4 v2 = yp[q * 3 + 2];
            float c[12] = {v0.x, v0.y, v0.z, v0.w,
                           v1.x, v1.y, v1.z, v1.w,
                           v2.x, v2.y, v2.z, v2.w};
            #pragma unroll
            for (int a = 0; a < 4; ++a) {
                float yx = c[a * 3 + 0], yy = c[a * 3 + 1], yz = c[a * 3 + 2];
                float d2 = qs + (yx * yx + yy * yy + yz * yz)
                              - 2.0f * (x0 * yx + x1 * yy + x2 * yz);
                d2 = (d2 >= 0.0f) ? d2 : 1e8f;
                m2 = fminf(m2, d2);
            }
        }
        float m = sqrtf(m2);
        int mk = mask[idx];
        dist_out[idx] = mk ? m : 0.0f;
        mask_out[idx] = mk ? 1.0f : 0.0f;
    }

    // ---- pack B fragments (weights now landed) ----
    short8 bf0[4], bf1[4];
    #pragma unroll
    for (int ks = 0; ks < 4; ++ks) {
        short8 t0, t1;
        #pragma unroll
        for (int j = 0; j < 8; ++j) {
            t0[j] = bfc(w0v[ks * 8 + j]);
            t1[j] = pad1 ? (short)0 : bfc(w1v[ks * 8 + j]);
        }
        bf0[ks] = t0;
        bf1[ks] = t1;
    }

    // ---------------- MFMA GEMV: 2-deep ks pipeline ----------------
    f32x4 acc[4][2];
    #pragma unroll
    for (int m = 0; m < 4; ++m) {
        acc[m][0] = (f32x4){bv0, bv0, bv0, bv0};
        acc[m][1] = (f32x4){bv1, bv1, bv1, bv1};
    }

    float4 xn0[4], xn1[4];
    #pragma unroll
    for (int ks = 0; ks < 4; ++ks) {
        if (ks < 3) {                        // issue next-stage loads first
            #pragma unroll
            for (int m = 0; m < 4; ++m) {
                const float* ap = xbase + (size_t)m * 16 * NH + (ks + 1) * 32;
                xn0[m] = *(const float4*)ap;
                xn1[m] = *(const float4*)(ap + 4);
            }
        }
        #pragma unroll
        for (int m = 0; m < 4; ++m) {
            float c[8] = {xc0[m].x, xc0[m].y, xc0[m].z, xc0[m].w,
                          xc1[m].x, xc1[m].y, xc1[m].z, xc1[m].w};
            short8 af;
            #pragma unroll
            for (int j = 0; j < 8; ++j) af[j] = bfc(c[j]);
            acc[m][0] = __builtin_amdgcn_mfma_f32_16x16x32_bf16(af, bf0[ks], acc[m][0], 0, 0, 0);
            acc[m][1] = __builtin_amdgcn_mfma_f32_16x16x32_bf16(af, bf1[ks], acc[m][1], 0, 0, 0);
        }
        #pragma unroll
        for (int m = 0; m < 4; ++m) {        // register rename, elided
            xc0[m] = xn0[m];
            xc1[m] = xn1[m];
        }
    }

    // ---------------- C -> LDS (wave-private, no barrier needed) ----------
    // C/D: col = lane&15, row = (lane>>4)*4 + reg. Stride 36 floats:
    // writes 2 lanes/bank = free; b128 reads evenly spread over bank quads.
    float* cw = cs + wv * (64 * 36);
    #pragma unroll
    for (int m = 0; m < 4; ++m)
        #pragma unroll
        for (int n = 0; n < 2; ++n)
            #pragma unroll
            for (int r = 0; r < 4; ++r)
                cw[(m * 16 + lkg * 4 + r) * 36 + n * 16 + lrow] = acc[m][n][r];

    // thread reads its own wave's region -> same-wave lgkmcnt ordering only
    const float* myrow = cs + wv * (64 * 36) + lane * 36;  // 144B-aligned
    float a[32];
    #pragma unroll
    for (int j = 0; j < 8; ++j)
        *(float4*)&a[4 * j] = *(const float4*)&myrow[4 * j];

    // ---------------- activations + stores ----------------
    const size_t ro = (size_t)idx * NG;

    // pi = softmax(a[0..9])
    float mx = a[0];
    #pragma unroll
    for (int g = 1; g < NG; ++g) mx = fmaxf(mx, a[g]);
    float e[NG], ssum = 0.0f;
    #pragma unroll
    for (int g = 0; g < NG; ++g) { e[g] = __expf(a[g] - mx); ssum += e[g]; }
    float inv = 1.0f / ssum;
    #pragma unroll
    for (int g = 0; g < 5; ++g)
        *(float2*)&out_pi[ro + 2 * g] = make_float2(e[2 * g] * inv,
                                                    e[2 * g + 1] * inv);

    // sigma = clip(leaky(a[10..19]) + 1.1, 1e-6, inf)
    #pragma unroll
    for (int g = 0; g < 5; ++g) {
        float xa = a[10 + 2 * g], xb = a[10 + 2 * g + 1];
        float va = fmaxf((xa >= 0.0f ? xa : 0.01f * xa) + 1.1f, 1e-6f);
        float vb = fmaxf((xb >= 0.0f ? xb : 0.01f * xb) + 1.1f, 1e-6f);
        *(float2*)&out_sg[ro + 2 * g] = make_float2(va, vb);
    }

    // mu = leaky(a[20..29]) + 1.0
    #pragma unroll
    for (int g = 0; g < 5; ++g) {
        float xa = a[20 + 2 * g], xb = a[20 + 2 * g + 1];
        float va = (xa >= 0.0f ? xa : 0.01f * xa) + 1.0f;
        float vb = (xb >= 0.0f ? xb : 0.01f * xb) + 1.0f;
        *(float2*)&out_mu[ro + 2 * g] = make_float2(va, vb);
    }
}

// ---------------------------------------------------------------------------
extern "C" void kernel_launch(void* const* d_in, const int* in_sizes, int n_in,
                              void* d_out, int out_size, void* d_ws, size_t ws_size,
                              hipStream_t stream) {
    const float* pos_l    = (const float*)d_in[0];
    const float* pos_p    = (const float*)d_in[1];
    const float* Interact = (const float*)d_in[2];
    const int*   mask     = (const int*)  d_in[3];
    const float* Wpi      = (const float*)d_in[4];
    const float* bpi      = (const float*)d_in[5];
    const float* Wsg      = (const float*)d_in[6];
    const float* bsg      = (const float*)d_in[7];
    const float* Wmu      = (const float*)d_in[8];
    const float* bmu      = (const float*)d_in[9];

    float* out      = (float*)d_out;
    float* out_pi   = out + OFF_PI;
    float* out_sg   = out + OFF_SIGMA;
    float* out_mu   = out + OFF_MU;
    float* out_dist = out + OFF_DIST;
    float* out_mask = out + OFF_MASK;

    hipLaunchKernelGGL(k_fused, dim3(ROWS / 256), dim3(256), 0, stream,
                       pos_l, pos_p, mask, Interact,
                       Wpi, bpi, Wsg, bsg, Wmu, bmu,
                       out_pi, out_sg, out_mu, out_dist, out_mask);
}

// Round 7
// 410.866 us; speedup vs baseline: 1.0256x; 1.0256x over previous
//
#include <hip/hip_runtime.h>
#include <cmath>

#define NB 16
#define NL 64
#define NP 512
#define NH 128
#define NG 10
#define ROWS (NB * NL * NP)          // 524288 rows

// output layout (flat float32, reference return order)
#define OFF_PI    ((size_t)0)
#define OFF_SIGMA ((size_t)5242880)
#define OFF_MU    ((size_t)10485760)
#define OFF_DIST  ((size_t)15728640)
#define OFF_MASK  ((size_t)16252928)

typedef __attribute__((ext_vector_type(8))) short short8;  // 8 bf16 = 4 VGPR
typedef __attribute__((ext_vector_type(4))) float f32x4;   // MFMA acc

// pack two f32 into one dword of two bf16 (round-nearest-even) -- R5-proven
__device__ __forceinline__ unsigned pk2(float a, float b) {
    unsigned ua = __float_as_uint(a);
    unsigned ub = __float_as_uint(b);
    ua = (ua + 0x7fffu + ((ua >> 16) & 1u)) >> 16;
    ub = (ub + 0x7fffu + ((ub >> 16) & 1u)) & 0xffff0000u;
    return ua | ub;
}

// ---------------------------------------------------------------------------
// Pack kernel: build the 8 KB bf16 B-fragment table in d_ws.
// Entry e = (ks*2+n)*64 + lane holds the short8 fragment for that lane:
// col = n*16 + (lane&15), k = ks*32 + (lane>>4)*8 + j  (same k-map as A).
// Cols: 0-9 pi | 10-19 sigma | 20-29 mu | 30,31 zero-pad.
// ---------------------------------------------------------------------------
__global__ __launch_bounds__(512) void k_pack(
    const float* __restrict__ Wpi, const float* __restrict__ Wsg,
    const float* __restrict__ Wmu, uint4* __restrict__ tbl)
{
    int e    = threadIdx.x;          // 512 entries
    int lane = e & 63;
    int n    = (e >> 6) & 1;
    int ks   = e >> 7;
    int lrow = lane & 15, lkg = lane >> 4;
    int col  = n * 16 + lrow;
    float w[8];
    #pragma unroll
    for (int j = 0; j < 8; ++j) {
        int k = ks * 32 + lkg * 8 + j;
        float v = 0.0f;
        if      (col < 10) v = Wpi[k * NG + col];
        else if (col < 20) v = Wsg[k * NG + col - 10];
        else if (col < 30) v = Wmu[k * NG + col - 20];
        w[j] = v;
    }
    uint4 u = {pk2(w[0], w[1]), pk2(w[2], w[3]),
               pk2(w[4], w[5]), pk2(w[6], w[7])};
    tbl[e] = u;
}

// ---------------------------------------------------------------------------
// Fused kernel: min-dist over 24 atoms + 3x GEMV [128 -> 30] via MFMA.
//
// R7 (on R5's verified structure):
//  - B-fragments come pre-packed from the d_ws table: 8 coalesced dwordx4
//    (32 VGPR as bf16) instead of R5's 64 stride-40 gathers on the MFMA
//    dependent path (R6's f32 hoist of the same data spilled: 64 f32 regs).
//  - X pipelined depth-2 over m-tiles (8+8 float4); m=0 + table loads
//    issued before dist so their latency hides under dist's VALU work.
// Peak live ~145 VGPR < 170 cap -> no spill (canary: WRITE_SIZE).
// ---------------------------------------------------------------------------
__global__ __launch_bounds__(256, 3) void k_fused(
    const float* __restrict__ pos_l,   // [B, NL, 3]
    const float* __restrict__ pos_p,   // [B, NP, 24, 3]
    const int*   __restrict__ mask,    // [B, NL, NP] (bool as int32)
    const float* __restrict__ X,       // [ROWS, 128]
    const uint4* __restrict__ wtbl,    // [4][2][64] bf16 fragments (d_ws)
    const float* __restrict__ bpi,
    const float* __restrict__ bsg,
    const float* __restrict__ bmu,
    float* __restrict__ out_pi,
    float* __restrict__ out_sg,
    float* __restrict__ out_mu,
    float* __restrict__ dist_out,
    float* __restrict__ mask_out)
{
    // per-wave C regions: [4 waves][64 rows][36 cols] f32 = 36864 B
    __shared__ __align__(16) float cs[4 * 64 * 36];

    const int tid  = threadIdx.x;
    const int wv   = tid >> 6;
    const int lane = tid & 63;
    const int lrow = lane & 15;              // A-row / C-col within tile
    const int lkg  = lane >> 4;              // k-group (8 k each)
    const int idx  = blockIdx.x * 256 + tid; // b*NL*NP + l*NP + p
    const size_t row0 = (size_t)blockIdx.x * 256;

    // ---- hoist B-fragment loads (coalesced, 8 KB table is L2/L3-hot) ----
    uint4 bu0[4], bu1[4];
    #pragma unroll
    for (int ks = 0; ks < 4; ++ks) {
        bu0[ks] = wtbl[(ks * 2 + 0) * 64 + lane];
        bu1[ks] = wtbl[(ks * 2 + 1) * 64 + lane];
    }

    // bias for acc init (f32 exact)
    const int c0 = lrow, c1 = lrow + 16;
    const float bv0 = (c0 < 10) ? bpi[c0] : bsg[c0 - 10];
    const float bv1 = (c1 < 20) ? bsg[c1 - 10] : (c1 < 30 ? bmu[c1 - 20] : 0.0f);

    // ---- issue m=0 X loads (in flight across dist) ----
    // thread covers rows (wv*64 + m*16 + lrow), k = ks*32 + lkg*8 .. +8
    const float* xbase = X + (row0 + wv * 64 + lrow) * NH + lkg * 8;
    float4 xc[8], xn[8];                     // [ks][half], current / next m
    #pragma unroll
    for (int q = 0; q < 8; ++q)
        xc[q] = *(const float4*)(xbase + (q >> 1) * 32 + (q & 1) * 4);

    // ---------------- distance part (R5-verified) ----------------
    {
        int p  = idx & (NP - 1);
        int bl = idx >> 9;                   // b*NL + l
        int b  = bl >> 6;

        const float* xl = pos_l + bl * 3;
        float x0 = xl[0], x1 = xl[1], x2 = xl[2];
        float qs = x0 * x0 + x1 * x1 + x2 * x2;

        const float4* yp = (const float4*)(pos_p + ((size_t)(b * NP + p)) * 72);

        // d2<0 -> NaN -> 10000 in the ref: clamp to 1e8 (=10000^2 exactly),
        // one sqrt of the min at the end.
        float m2 = 1e30f;
        #pragma unroll
        for (int q = 0; q < 6; ++q) {
            float4 v0 = yp[q * 3 + 0];
            float4 v1 = yp[q * 3 + 1];
            float4 v2 = yp[q * 3 + 2];
            float c[12] = {v0.x, v0.y, v0.z, v0.w,
                           v1.x, v1.y, v1.z, v1.w,
                           v2.x, v2.y, v2.z, v2.w};
            #pragma unroll
            for (int a = 0; a < 4; ++a) {
                float yx = c[a * 3 + 0], yy = c[a * 3 + 1], yz = c[a * 3 + 2];
                float d2 = qs + (yx * yx + yy * yy + yz * yz)
                              - 2.0f * (x0 * yx + x1 * yy + x2 * yz);
                d2 = (d2 >= 0.0f) ? d2 : 1e8f;
                m2 = fminf(m2, d2);
            }
        }
        float m = sqrtf(m2);
        int mk = mask[idx];
        dist_out[idx] = mk ? m : 0.0f;
        mask_out[idx] = mk ? 1.0f : 0.0f;
    }

    // ---------------- MFMA GEMV: depth-2 pipeline over m ----------------
    f32x4 acc[4][2];
    #pragma unroll
    for (int m = 0; m < 4; ++m) {
        acc[m][0] = (f32x4){bv0, bv0, bv0, bv0};
        acc[m][1] = (f32x4){bv1, bv1, bv1, bv1};
    }

    #pragma unroll
    for (int m = 0; m < 4; ++m) {
        if (m < 3) {                         // issue next m-tile's loads
            const float* ap = xbase + (size_t)(m + 1) * 16 * NH;
            #pragma unroll
            for (int q = 0; q < 8; ++q)
                xn[q] = *(const float4*)(ap + (q >> 1) * 32 + (q & 1) * 4);
        }
        #pragma unroll
        for (int ks = 0; ks < 4; ++ks) {
            float4 lo = xc[ks * 2], hi = xc[ks * 2 + 1];
            uint4 ua = {pk2(lo.x, lo.y), pk2(lo.z, lo.w),
                        pk2(hi.x, hi.y), pk2(hi.z, hi.w)};
            short8 af = __builtin_bit_cast(short8, ua);
            acc[m][0] = __builtin_amdgcn_mfma_f32_16x16x32_bf16(
                af, __builtin_bit_cast(short8, bu0[ks]), acc[m][0], 0, 0, 0);
            acc[m][1] = __builtin_amdgcn_mfma_f32_16x16x32_bf16(
                af, __builtin_bit_cast(short8, bu1[ks]), acc[m][1], 0, 0, 0);
        }
        #pragma unroll
        for (int q = 0; q < 8; ++q) xc[q] = xn[q];   // rename, elided
    }

    // ---------------- C -> LDS (wave-private, no barrier) ----------------
    // C/D layout (m89/m91): col = lane&15, row = (lane>>4)*4 + reg.
    float* cw = cs + wv * (64 * 36);
    #pragma unroll
    for (int m = 0; m < 4; ++m)
        #pragma unroll
        for (int n = 0; n < 2; ++n)
            #pragma unroll
            for (int r = 0; r < 4; ++r)
                cw[(m * 16 + lkg * 4 + r) * 36 + n * 16 + lrow] = acc[m][n][r];

    // thread reads its own wave's region -> same-wave lgkmcnt ordering only
    const float* myrow = cs + wv * (64 * 36) + lane * 36;  // 144B-aligned
    float a[32];
    #pragma unroll
    for (int j = 0; j < 8; ++j)
        *(float4*)&a[4 * j] = *(const float4*)&myrow[4 * j];

    // ---------------- activations + stores ----------------
    const size_t ro = (size_t)idx * NG;

    // pi = softmax(a[0..9])
    float mx = a[0];
    #pragma unroll
    for (int g = 1; g < NG; ++g) mx = fmaxf(mx, a[g]);
    float e[NG], ssum = 0.0f;
    #pragma unroll
    for (int g = 0; g < NG; ++g) { e[g] = __expf(a[g] - mx); ssum += e[g]; }
    float inv = 1.0f / ssum;
    #pragma unroll
    for (int g = 0; g < 5; ++g)
        *(float2*)&out_pi[ro + 2 * g] = make_float2(e[2 * g] * inv,
                                                    e[2 * g + 1] * inv);

    // sigma = clip(leaky(a[10..19]) + 1.1, 1e-6, inf)
    #pragma unroll
    for (int g = 0; g < 5; ++g) {
        float xa = a[10 + 2 * g], xb = a[10 + 2 * g + 1];
        float va = fmaxf((xa >= 0.0f ? xa : 0.01f * xa) + 1.1f, 1e-6f);
        float vb = fmaxf((xb >= 0.0f ? xb : 0.01f * xb) + 1.1f, 1e-6f);
        *(float2*)&out_sg[ro + 2 * g] = make_float2(va, vb);
    }

    // mu = leaky(a[20..29]) + 1.0
    #pragma unroll
    for (int g = 0; g < 5; ++g) {
        float xa = a[20 + 2 * g], xb = a[20 + 2 * g + 1];
        float va = (xa >= 0.0f ? xa : 0.01f * xa) + 1.0f;
        float vb = (xb >= 0.0f ? xb : 0.01f * xb) + 1.0f;
        *(float2*)&out_mu[ro + 2 * g] = make_float2(va, vb);
    }
}

// ---------------------------------------------------------------------------
extern "C" void kernel_launch(void* const* d_in, const int* in_sizes, int n_in,
                              void* d_out, int out_size, void* d_ws, size_t ws_size,
                              hipStream_t stream) {
    const float* pos_l    = (const float*)d_in[0];
    const float* pos_p    = (const float*)d_in[1];
    const float* Interact = (const float*)d_in[2];
    const int*   mask     = (const int*)  d_in[3];
    const float* Wpi      = (const float*)d_in[4];
    const float* bpi      = (const float*)d_in[5];
    const float* Wsg      = (const float*)d_in[6];
    const float* bsg      = (const float*)d_in[7];
    const float* Wmu      = (const float*)d_in[8];
    const float* bmu      = (const float*)d_in[9];

    float* out      = (float*)d_out;
    float* out_pi   = out + OFF_PI;
    float* out_sg   = out + OFF_SIGMA;
    float* out_mu   = out + OFF_MU;
    float* out_dist = out + OFF_DIST;
    float* out_mask = out + OFF_MASK;

    uint4* wtbl = (uint4*)d_ws;              // 8 KB fragment table

    hipLaunchKernelGGL(k_pack, dim3(1), dim3(512), 0, stream,
                       Wpi, Wsg, Wmu, wtbl);
    hipLaunchKernelGGL(k_fused, dim3(ROWS / 256), dim3(256), 0, stream,
                       pos_l, pos_p, mask, Interact, wtbl,
                       bpi, bsg, bmu,
                       out_pi, out_sg, out_mu, out_dist, out_mask);
}